// Round 3
// baseline (1063.865 us; speedup 1.0000x reference)
//
#include <hip/hip_runtime.h>
#include <math.h>

#define IN_C 64
#define HID_C 128
#define OUT_C 64

// ============ CSR build (runs every call; graph-capture safe) ============
__global__ void k_hist(const int* __restrict__ dst, int* __restrict__ cnt, int E) {
  int i = blockIdx.x * blockDim.x + threadIdx.x;
  int stride = gridDim.x * blockDim.x;
  for (int e = i; e < E; e += stride) atomicAdd(&cnt[dst[e]], 1);
}

__global__ __launch_bounds__(256) void k_blocksum(const int* __restrict__ cnt,
                                                  int* __restrict__ partial, int N) {
  __shared__ int red[256];
  int b = blockIdx.x, t = threadIdx.x;
  int base = b * 1024 + t * 4;
  int s = 0;
#pragma unroll
  for (int k = 0; k < 4; ++k) { int i = base + k; if (i < N) s += cnt[i]; }
  red[t] = s;
  __syncthreads();
  for (int off = 128; off > 0; off >>= 1) {
    if (t < off) red[t] += red[t + off];
    __syncthreads();
  }
  if (t == 0) partial[b] = red[0];
}

__global__ __launch_bounds__(128) void k_scanpart(int* __restrict__ partial, int nb) {
  __shared__ int s[128];
  int t = threadIdx.x;
  int v = (t < nb) ? partial[t] : 0;
  s[t] = v;
  __syncthreads();
  for (int off = 1; off < 128; off <<= 1) {
    int add = (t >= off) ? s[t - off] : 0;
    __syncthreads();
    s[t] += add;
    __syncthreads();
  }
  int ex = (t == 0) ? 0 : s[t - 1];
  if (t < nb) partial[t] = ex;
}

__global__ __launch_bounds__(256) void k_scanwrite(const int* __restrict__ cnt,
                                                   const int* __restrict__ partial,
                                                   int* __restrict__ row_start,
                                                   int* __restrict__ cursor, int N) {
  __shared__ int s[256];
  int b = blockIdx.x, t = threadIdx.x;
  int base = b * 1024 + t * 4;
  int d[4];
  int sum = 0;
#pragma unroll
  for (int k = 0; k < 4; ++k) { int i = base + k; d[k] = (i < N) ? cnt[i] : 0; sum += d[k]; }
  s[t] = sum;
  __syncthreads();
  for (int off = 1; off < 256; off <<= 1) {
    int add = (t >= off) ? s[t - off] : 0;
    __syncthreads();
    s[t] += add;
    __syncthreads();
  }
  int ex = (t == 0) ? 0 : s[t - 1];
  int off0 = partial[b] + ex;
#pragma unroll
  for (int k = 0; k < 4; ++k) {
    int i = base + k;
    if (i < N) { row_start[i] = off0; cursor[i] = off0; off0 += d[k]; }
  }
}

__global__ void k_fill(const int* __restrict__ src, const int* __restrict__ dst,
                       int* __restrict__ cursor, int* __restrict__ csr, int E) {
  int i = blockIdx.x * blockDim.x + threadIdx.x;
  int stride = gridDim.x * blockDim.x;
  for (int e = i; e < E; e += stride) {
    int d = dst[e];
    int pos = atomicAdd(&cursor[d], 1);
    csr[pos] = src[e];
  }
}

// ============ gather 1: agg1[i] = mean_{j in N(i)} x[j]  (64ch, wave/node) ====
__global__ __launch_bounds__(256) void k_gather1(const float* __restrict__ x,
                                                 const int* __restrict__ csr,
                                                 const int* __restrict__ row_start,
                                                 const int* __restrict__ cnt,
                                                 float* __restrict__ agg, int N) {
  int wid = (blockIdx.x * blockDim.x + threadIdx.x) >> 6;
  int lane = threadIdx.x & 63;
  if (wid >= N) return;
  int start = row_start[wid];
  int c = cnt[wid];
  int j = start, end = start + c;
  float v = 0.f;
  for (; j + 3 < end; j += 4) {
    int s0 = csr[j], s1 = csr[j + 1], s2 = csr[j + 2], s3 = csr[j + 3];
    float a0 = x[s0 * IN_C + lane];
    float a1 = x[s1 * IN_C + lane];
    float a2 = x[s2 * IN_C + lane];
    float a3 = x[s3 * IN_C + lane];
    v += a0 + a1 + a2 + a3;
  }
  for (; j < end; ++j) v += x[csr[j] * IN_C + lane];
  float inv = 1.0f / fmaxf((float)c, 1.0f);
  agg[wid * IN_C + lane] = v * inv;
}

// ============ fused GEMM: h = relu([agg1|x] @ [W1l|W1r]^T + b1) (LDS only),
//              z = h @ W2l^T,  r = h @ W2r^T  ==============================
// 512 thr. Phase1: o1=t&127 (h channel), q1=t>>7 selects 32-wide K-slice of
// the concatenated [agg(64)|x(64)] input. Phase2: u=t&127 (u<64: z[u], else
// r[u-64]), q2=t>>7 selects 32-wide K-slice of h(128). Weights: 32 fl/phase
// in VGPRs, loaded once per block. Feature LDS reads are wave-uniform
// broadcasts. 4-way partial reduce via LDS atomicAdd (ds_add_f32).
__global__ __launch_bounds__(512) void k_fused_linear(
    const float* __restrict__ agg, const float* __restrict__ x,
    const float* __restrict__ W1l, const float* __restrict__ W1r,
    const float* __restrict__ b1,
    const float* __restrict__ W2l, const float* __restrict__ W2r,
    float* __restrict__ z, float* __restrict__ r, int N) {
  constexpr int NT = 16;
  __shared__ __align__(16) float sA[NT][IN_C];
  __shared__ __align__(16) float sX[NT][IN_C];
  __shared__ __align__(16) float sh[NT][HID_C];
  __shared__ __align__(16) float szr[NT][HID_C];
  __shared__ float sb1[HID_C];
  int t = threadIdx.x;
  int o1 = t & 127, q1 = t >> 7;       // phase-1 identity
  int u = t & 127, q2 = t >> 7;        // phase-2 identity

  // weight slices -> VGPRs (once per block)
  const float4* w1base = (const float4*)((q1 < 2)
      ? (W1l + o1 * IN_C + 32 * q1)
      : (W1r + o1 * IN_C + 32 * (q1 - 2)));
  const float4* w2base = (const float4*)((u < 64)
      ? (W2l + u * HID_C + 32 * q2)
      : (W2r + (u - 64) * HID_C + 32 * q2));
  float4 wp[8], wq[8];
#pragma unroll
  for (int k = 0; k < 8; ++k) { wp[k] = w1base[k]; wq[k] = w2base[k]; }
  if (t < HID_C) sb1[t] = b1[t];
  __syncthreads();

  // phase-1 feature base: rows of sA/sX are 64 floats contiguous
  const float* f1base = (q1 < 2) ? (&sA[0][0] + 32 * q1) : (&sX[0][0] + 32 * (q1 - 2));
  float* shf = &sh[0][0];
  float* szrf = &szr[0][0];

  int ntiles = (N + NT - 1) / NT;
  for (int tile = blockIdx.x; tile < ntiles; tile += gridDim.x) {
    int base = tile * NT;
    // stage features; init sh=b1, szr=0
    for (int i = t; i < NT * IN_C; i += 512) {
      int n = i >> 6, c = i & 63;
      int idx = base + n;
      float a = 0.f, xv = 0.f;
      if (idx < N) { a = agg[idx * IN_C + c]; xv = x[idx * IN_C + c]; }
      sA[n][c] = a;
      sX[n][c] = xv;
    }
    for (int i = t; i < NT * HID_C; i += 512) {
      shf[i] = sb1[i & 127];
      szrf[i] = 0.f;
    }
    __syncthreads();
    // phase 1: h partials
#pragma unroll 4
    for (int n = 0; n < NT; ++n) {
      const float4* f = (const float4*)(f1base + n * IN_C);
      float acc = 0.f;
#pragma unroll
      for (int k = 0; k < 8; ++k) {
        float4 fv = f[k];
        acc = fmaf(fv.x, wp[k].x, acc);
        acc = fmaf(fv.y, wp[k].y, acc);
        acc = fmaf(fv.z, wp[k].z, acc);
        acc = fmaf(fv.w, wp[k].w, acc);
      }
      atomicAdd(&sh[n][o1], acc);
    }
    __syncthreads();
    // relu
    for (int i = t; i < NT * HID_C; i += 512) shf[i] = fmaxf(shf[i], 0.f);
    __syncthreads();
    // phase 2: z,r partials
#pragma unroll 4
    for (int n = 0; n < NT; ++n) {
      const float4* f = (const float4*)(&sh[n][32 * q2]);
      float acc = 0.f;
#pragma unroll
      for (int k = 0; k < 8; ++k) {
        float4 fv = f[k];
        acc = fmaf(fv.x, wq[k].x, acc);
        acc = fmaf(fv.y, wq[k].y, acc);
        acc = fmaf(fv.z, wq[k].z, acc);
        acc = fmaf(fv.w, wq[k].w, acc);
      }
      atomicAdd(&szr[n][u], acc);
    }
    __syncthreads();
    // store z | r
    for (int i = t; i < NT * HID_C; i += 512) {
      int n = i >> 7, c = i & 127;
      int idx = base + n;
      if (idx < N) {
        if (c < 64) z[idx * 64 + c] = szr[n][c];
        else        r[idx * 64 + (c - 64)] = szr[n][c];
      }
    }
    __syncthreads();
  }
}

// ==== gather 2 + epilogue: out = sigmoid(mean_{j} z[j] + r[i] + b2) ========
__global__ __launch_bounds__(256) void k_gather2b(const float* __restrict__ z,
                                                  const float* __restrict__ r,
                                                  const float* __restrict__ b2,
                                                  const int* __restrict__ csr,
                                                  const int* __restrict__ row_start,
                                                  const int* __restrict__ cnt,
                                                  float* __restrict__ out, int N) {
  int wid = (blockIdx.x * blockDim.x + threadIdx.x) >> 6;
  int lane = threadIdx.x & 63;
  if (wid >= N) return;
  int start = row_start[wid];
  int c = cnt[wid];
  int j = start, end = start + c;
  float v = 0.f;
  for (; j + 3 < end; j += 4) {
    int s0 = csr[j], s1 = csr[j + 1], s2 = csr[j + 2], s3 = csr[j + 3];
    float a0 = z[s0 * 64 + lane];
    float a1 = z[s1 * 64 + lane];
    float a2 = z[s2 * 64 + lane];
    float a3 = z[s3 * 64 + lane];
    v += a0 + a1 + a2 + a3;
  }
  for (; j < end; ++j) v += z[csr[j] * 64 + lane];
  float inv = 1.0f / fmaxf((float)c, 1.0f);
  float pre = v * inv + r[wid * 64 + lane] + b2[lane];
  out[wid * 64 + lane] = 1.0f / (1.0f + __expf(-pre));
}

extern "C" void kernel_launch(void* const* d_in, const int* in_sizes, int n_in,
                              void* d_out, int out_size, void* d_ws, size_t ws_size,
                              hipStream_t stream) {
  const float* x   = (const float*)d_in[0];
  const int*   ei  = (const int*)d_in[1];
  const float* W1l = (const float*)d_in[2];
  const float* W1r = (const float*)d_in[3];
  const float* b1  = (const float*)d_in[4];
  const float* W2l = (const float*)d_in[5];
  const float* W2r = (const float*)d_in[6];
  const float* b2  = (const float*)d_in[7];
  float* out = (float*)d_out;

  int N = in_sizes[0] / IN_C;
  int E = in_sizes[1] / 2;
  const int* src = ei;
  const int* dst = ei + E;

  // ws layout: [cnt N][row_start N][cursor N][partial 128][csr E]
  //            [agg1 N*64 f][z N*64 f][r N*64 f]
  char* ws = (char*)d_ws;
  size_t off = 0;
  auto alignup = [](size_t v) { return (v + 511) & ~(size_t)511; };
  int* cnt = (int*)(ws + off);        off = alignup(off + (size_t)N * 4);
  int* row_start = (int*)(ws + off);  off = alignup(off + (size_t)N * 4);
  int* cursor = (int*)(ws + off);     off = alignup(off + (size_t)N * 4);
  int* partial = (int*)(ws + off);    off = alignup(off + 128 * 4);
  int* csr = (int*)(ws + off);        off = alignup(off + (size_t)E * 4);
  float* aggbuf = (float*)(ws + off); off = alignup(off + (size_t)N * IN_C * 4);
  float* zbuf = (float*)(ws + off);   off = alignup(off + (size_t)N * 64 * 4);
  float* rbuf = (float*)(ws + off);

  int NB = (N + 1023) / 1024;  // scan chunks (<=128 supported)

  // CSR build
  hipMemsetAsync(cnt, 0, (size_t)N * 4, stream);
  k_hist<<<2048, 256, 0, stream>>>(dst, cnt, E);
  k_blocksum<<<NB, 256, 0, stream>>>(cnt, partial, N);
  k_scanpart<<<1, 128, 0, stream>>>(partial, NB);
  k_scanwrite<<<NB, 256, 0, stream>>>(cnt, partial, row_start, cursor, N);
  k_fill<<<2048, 256, 0, stream>>>(src, dst, cursor, csr, E);

  // layer 1 aggregation
  k_gather1<<<(N + 3) / 4, 256, 0, stream>>>(x, csr, row_start, cnt, aggbuf, N);
  // fused: linear1 + relu + linear2 (both halves), h stays in LDS
  k_fused_linear<<<1024, 512, 0, stream>>>(aggbuf, x, W1l, W1r, b1, W2l, W2r,
                                           zbuf, rbuf, N);
  // layer 2 aggregation + bias + sigmoid
  k_gather2b<<<(N + 3) / 4, 256, 0, stream>>>(zbuf, rbuf, b2, csr, row_start, cnt,
                                              out, N);
}

// Round 4
// 548.475 us; speedup vs baseline: 1.9397x; 1.9397x over previous
//
#include <hip/hip_runtime.h>
#include <math.h>

#define IN_C 64
#define HID_C 128
#define OUT_C 64

// ============ CSR build (runs every call; graph-capture safe) ============
__global__ void k_hist(const int* __restrict__ dst, int* __restrict__ cnt, int E) {
  int i = blockIdx.x * blockDim.x + threadIdx.x;
  int stride = gridDim.x * blockDim.x;
  for (int e = i; e < E; e += stride) atomicAdd(&cnt[dst[e]], 1);
}

__global__ __launch_bounds__(256) void k_blocksum(const int* __restrict__ cnt,
                                                  int* __restrict__ partial, int N) {
  __shared__ int red[256];
  int b = blockIdx.x, t = threadIdx.x;
  int base = b * 1024 + t * 4;
  int s = 0;
#pragma unroll
  for (int k = 0; k < 4; ++k) { int i = base + k; if (i < N) s += cnt[i]; }
  red[t] = s;
  __syncthreads();
  for (int off = 128; off > 0; off >>= 1) {
    if (t < off) red[t] += red[t + off];
    __syncthreads();
  }
  if (t == 0) partial[b] = red[0];
}

__global__ __launch_bounds__(128) void k_scanpart(int* __restrict__ partial, int nb) {
  __shared__ int s[128];
  int t = threadIdx.x;
  int v = (t < nb) ? partial[t] : 0;
  s[t] = v;
  __syncthreads();
  for (int off = 1; off < 128; off <<= 1) {
    int add = (t >= off) ? s[t - off] : 0;
    __syncthreads();
    s[t] += add;
    __syncthreads();
  }
  int ex = (t == 0) ? 0 : s[t - 1];
  if (t < nb) partial[t] = ex;
}

__global__ __launch_bounds__(256) void k_scanwrite(const int* __restrict__ cnt,
                                                   const int* __restrict__ partial,
                                                   int* __restrict__ row_start,
                                                   int* __restrict__ cursor, int N) {
  __shared__ int s[256];
  int b = blockIdx.x, t = threadIdx.x;
  int base = b * 1024 + t * 4;
  int d[4];
  int sum = 0;
#pragma unroll
  for (int k = 0; k < 4; ++k) { int i = base + k; d[k] = (i < N) ? cnt[i] : 0; sum += d[k]; }
  s[t] = sum;
  __syncthreads();
  for (int off = 1; off < 256; off <<= 1) {
    int add = (t >= off) ? s[t - off] : 0;
    __syncthreads();
    s[t] += add;
    __syncthreads();
  }
  int ex = (t == 0) ? 0 : s[t - 1];
  int off0 = partial[b] + ex;
#pragma unroll
  for (int k = 0; k < 4; ++k) {
    int i = base + k;
    if (i < N) { row_start[i] = off0; cursor[i] = off0; off0 += d[k]; }
  }
}

__global__ void k_fill(const int* __restrict__ src, const int* __restrict__ dst,
                       int* __restrict__ cursor, int* __restrict__ csr, int E) {
  int i = blockIdx.x * blockDim.x + threadIdx.x;
  int stride = gridDim.x * blockDim.x;
  for (int e = i; e < E; e += stride) {
    int d = dst[e];
    int pos = atomicAdd(&cursor[d], 1);
    csr[pos] = src[e];
  }
}

// ============ gather 1: agg1[i] = mean_{j in N(i)} x[j]  (64ch, wave/node) ====
__global__ __launch_bounds__(256) void k_gather1(const float* __restrict__ x,
                                                 const int* __restrict__ csr,
                                                 const int* __restrict__ row_start,
                                                 const int* __restrict__ cnt,
                                                 float* __restrict__ agg, int N) {
  int wid = (blockIdx.x * blockDim.x + threadIdx.x) >> 6;
  int lane = threadIdx.x & 63;
  if (wid >= N) return;
  int start = row_start[wid];
  int c = cnt[wid];
  int j = start, end = start + c;
  float v = 0.f;
  for (; j + 3 < end; j += 4) {
    int s0 = csr[j], s1 = csr[j + 1], s2 = csr[j + 2], s3 = csr[j + 3];
    float a0 = x[s0 * IN_C + lane];
    float a1 = x[s1 * IN_C + lane];
    float a2 = x[s2 * IN_C + lane];
    float a3 = x[s3 * IN_C + lane];
    v += a0 + a1 + a2 + a3;
  }
  for (; j < end; ++j) v += x[csr[j] * IN_C + lane];
  float inv = 1.0f / fmaxf((float)c, 1.0f);
  agg[wid * IN_C + lane] = v * inv;
}

// ============ register-blocked fp32 GEMM kernels ============
// Shared design: C[64n x 128c tile] = A[64n x 128k] @ Wt[128k x 128c].
// 512 thr: cg=t&31 (c0=cg*4), ng=t>>5 (nodes ng+16j). 16 accumulators.
// W staged K-major (pad 132) in LDS once per block (persistent grid).
// A reads are wave-broadcast (conflict-free); W reads 4-way aliased (ok).

#define FMA4(ACC, S, W4)                      \
  ACC.x = fmaf((S), (W4).x, ACC.x);           \
  ACC.y = fmaf((S), (W4).y, ACC.y);           \
  ACC.z = fmaf((S), (W4).z, ACC.z);           \
  ACC.w = fmaf((S), (W4).w, ACC.w);

// layer 1: h = relu([agg|x] @ [W1l|W1r]^T + b1)
__global__ __launch_bounds__(512) void k_lin1(
    const float* __restrict__ agg, const float* __restrict__ x,
    const float* __restrict__ W1l, const float* __restrict__ W1r,
    const float* __restrict__ b1, float* __restrict__ h, int N) {
  __shared__ __align__(16) float sW[128 * 132];
  __shared__ __align__(16) float sA[64 * 128];
  int t = threadIdx.x;
  // stage W transposed: sW[k][c], k<64 from W1l (agg half), k>=64 from W1r (x half)
  for (int i = t; i < 64 * 128; i += 512) {
    int k = i & 63, c = i >> 6;  // i = c*64+k : coalesced global read
    sW[k * 132 + c] = W1l[i];
    sW[(k + 64) * 132 + c] = W1r[i];
  }
  int cg = t & 31, ng = t >> 5;
  int c0 = cg * 4;
  float4 bias = ((const float4*)b1)[cg];
  const float4* agg4 = (const float4*)agg;
  const float4* x4 = (const float4*)x;
  __syncthreads();

  int ntiles = (N + 63) >> 6;
  for (int tile = blockIdx.x; tile < ntiles; tile += gridDim.x) {
    int base = tile << 6;
    // stage A tile: sA[n][k] = k<64 ? agg[node][k] : x[node][k-64]
#pragma unroll
    for (int j = 0; j < 4; ++j) {
      int idx = (t + j * 512) << 2;  // float index in [0, 8192)
      int n = idx >> 7, k = idx & 127;
      int node = base + n;
      float4 v = {0.f, 0.f, 0.f, 0.f};
      if (node < N) v = (k < 64) ? agg4[(node * 64 + k) >> 2]
                                 : x4[(node * 64 + (k - 64)) >> 2];
      *(float4*)(sA + n * 128 + k) = v;
    }
    __syncthreads();
    float4 acc0 = {0, 0, 0, 0}, acc1 = {0, 0, 0, 0}, acc2 = {0, 0, 0, 0}, acc3 = {0, 0, 0, 0};
#pragma unroll 4
    for (int k = 0; k < 128; k += 4) {
      float4 a0 = *(const float4*)(sA + (ng + 0) * 128 + k);
      float4 a1 = *(const float4*)(sA + (ng + 16) * 128 + k);
      float4 a2 = *(const float4*)(sA + (ng + 32) * 128 + k);
      float4 a3 = *(const float4*)(sA + (ng + 48) * 128 + k);
      float4 w0 = *(const float4*)(sW + (k + 0) * 132 + c0);
      float4 w1 = *(const float4*)(sW + (k + 1) * 132 + c0);
      float4 w2 = *(const float4*)(sW + (k + 2) * 132 + c0);
      float4 w3 = *(const float4*)(sW + (k + 3) * 132 + c0);
      FMA4(acc0, a0.x, w0) FMA4(acc1, a1.x, w0) FMA4(acc2, a2.x, w0) FMA4(acc3, a3.x, w0)
      FMA4(acc0, a0.y, w1) FMA4(acc1, a1.y, w1) FMA4(acc2, a2.y, w1) FMA4(acc3, a3.y, w1)
      FMA4(acc0, a0.z, w2) FMA4(acc1, a1.z, w2) FMA4(acc2, a2.z, w2) FMA4(acc3, a3.z, w2)
      FMA4(acc0, a0.w, w3) FMA4(acc1, a1.w, w3) FMA4(acc2, a2.w, w3) FMA4(acc3, a3.w, w3)
    }
    // epilogue: bias + relu, store
    float4 accs[4] = {acc0, acc1, acc2, acc3};
#pragma unroll
    for (int j = 0; j < 4; ++j) {
      int node = base + ng + 16 * j;
      if (node < N) {
        float4 hv;
        hv.x = fmaxf(accs[j].x + bias.x, 0.f);
        hv.y = fmaxf(accs[j].y + bias.y, 0.f);
        hv.z = fmaxf(accs[j].z + bias.z, 0.f);
        hv.w = fmaxf(accs[j].w + bias.w, 0.f);
        *(float4*)(h + node * 128 + c0) = hv;
      }
    }
    __syncthreads();
  }
}

// layer 2: z = h @ W2l^T, r = h @ W2r^T (bias+sigmoid deferred to gather2b)
__global__ __launch_bounds__(512) void k_lin2(
    const float* __restrict__ h, const float* __restrict__ W2l,
    const float* __restrict__ W2r, float* __restrict__ z,
    float* __restrict__ r, int N) {
  __shared__ __align__(16) float sW[128 * 132];
  __shared__ __align__(16) float sA[64 * 128];
  int t = threadIdx.x;
  // stage W transposed: sW[k][c], c<64 -> W2l row c, c>=64 -> W2r row c-64
  for (int i = t; i < 64 * 128; i += 512) {
    int k = i & 127, c = i >> 7;  // i = c*128+k : coalesced global read
    sW[k * 132 + c] = W2l[i];
    sW[k * 132 + 64 + c] = W2r[i];
  }
  int cg = t & 31, ng = t >> 5;
  int c0 = cg * 4;
  const float4* h4 = (const float4*)h;
  __syncthreads();

  int ntiles = (N + 63) >> 6;
  for (int tile = blockIdx.x; tile < ntiles; tile += gridDim.x) {
    int base = tile << 6;
#pragma unroll
    for (int j = 0; j < 4; ++j) {
      int idx = (t + j * 512) << 2;
      int n = idx >> 7, k = idx & 127;
      int node = base + n;
      float4 v = {0.f, 0.f, 0.f, 0.f};
      if (node < N) v = h4[(node * 128 + k) >> 2];
      *(float4*)(sA + n * 128 + k) = v;
    }
    __syncthreads();
    float4 acc0 = {0, 0, 0, 0}, acc1 = {0, 0, 0, 0}, acc2 = {0, 0, 0, 0}, acc3 = {0, 0, 0, 0};
#pragma unroll 4
    for (int k = 0; k < 128; k += 4) {
      float4 a0 = *(const float4*)(sA + (ng + 0) * 128 + k);
      float4 a1 = *(const float4*)(sA + (ng + 16) * 128 + k);
      float4 a2 = *(const float4*)(sA + (ng + 32) * 128 + k);
      float4 a3 = *(const float4*)(sA + (ng + 48) * 128 + k);
      float4 w0 = *(const float4*)(sW + (k + 0) * 132 + c0);
      float4 w1 = *(const float4*)(sW + (k + 1) * 132 + c0);
      float4 w2 = *(const float4*)(sW + (k + 2) * 132 + c0);
      float4 w3 = *(const float4*)(sW + (k + 3) * 132 + c0);
      FMA4(acc0, a0.x, w0) FMA4(acc1, a1.x, w0) FMA4(acc2, a2.x, w0) FMA4(acc3, a3.x, w0)
      FMA4(acc0, a0.y, w1) FMA4(acc1, a1.y, w1) FMA4(acc2, a2.y, w1) FMA4(acc3, a3.y, w1)
      FMA4(acc0, a0.z, w2) FMA4(acc1, a1.z, w2) FMA4(acc2, a2.z, w2) FMA4(acc3, a3.z, w2)
      FMA4(acc0, a0.w, w3) FMA4(acc1, a1.w, w3) FMA4(acc2, a2.w, w3) FMA4(acc3, a3.w, w3)
    }
    float4 accs[4] = {acc0, acc1, acc2, acc3};
#pragma unroll
    for (int j = 0; j < 4; ++j) {
      int node = base + ng + 16 * j;
      if (node < N) {
        if (c0 < 64) *(float4*)(z + node * 64 + c0) = accs[j];
        else         *(float4*)(r + node * 64 + (c0 - 64)) = accs[j];
      }
    }
    __syncthreads();
  }
}

// ==== gather 2 + epilogue: out = sigmoid(mean_{j} z[j] + r[i] + b2) ========
__global__ __launch_bounds__(256) void k_gather2b(const float* __restrict__ z,
                                                  const float* __restrict__ r,
                                                  const float* __restrict__ b2,
                                                  const int* __restrict__ csr,
                                                  const int* __restrict__ row_start,
                                                  const int* __restrict__ cnt,
                                                  float* __restrict__ out, int N) {
  int wid = (blockIdx.x * blockDim.x + threadIdx.x) >> 6;
  int lane = threadIdx.x & 63;
  if (wid >= N) return;
  int start = row_start[wid];
  int c = cnt[wid];
  int j = start, end = start + c;
  float v = 0.f;
  for (; j + 3 < end; j += 4) {
    int s0 = csr[j], s1 = csr[j + 1], s2 = csr[j + 2], s3 = csr[j + 3];
    float a0 = z[s0 * 64 + lane];
    float a1 = z[s1 * 64 + lane];
    float a2 = z[s2 * 64 + lane];
    float a3 = z[s3 * 64 + lane];
    v += a0 + a1 + a2 + a3;
  }
  for (; j < end; ++j) v += z[csr[j] * 64 + lane];
  float inv = 1.0f / fmaxf((float)c, 1.0f);
  float pre = v * inv + r[wid * 64 + lane] + b2[lane];
  out[wid * 64 + lane] = 1.0f / (1.0f + __expf(-pre));
}

extern "C" void kernel_launch(void* const* d_in, const int* in_sizes, int n_in,
                              void* d_out, int out_size, void* d_ws, size_t ws_size,
                              hipStream_t stream) {
  const float* x   = (const float*)d_in[0];
  const int*   ei  = (const int*)d_in[1];
  const float* W1l = (const float*)d_in[2];
  const float* W1r = (const float*)d_in[3];
  const float* b1  = (const float*)d_in[4];
  const float* W2l = (const float*)d_in[5];
  const float* W2r = (const float*)d_in[6];
  const float* b2  = (const float*)d_in[7];
  float* out = (float*)d_out;

  int N = in_sizes[0] / IN_C;
  int E = in_sizes[1] / 2;
  const int* src = ei;
  const int* dst = ei + E;

  // ws layout: [cnt N][row_start N][cursor N][partial 128][csr E]
  //            [agg1 N*64 f][z N*64 f][r N*64 f][h N*128 f]
  char* ws = (char*)d_ws;
  size_t off = 0;
  auto alignup = [](size_t v) { return (v + 511) & ~(size_t)511; };
  int* cnt = (int*)(ws + off);        off = alignup(off + (size_t)N * 4);
  int* row_start = (int*)(ws + off);  off = alignup(off + (size_t)N * 4);
  int* cursor = (int*)(ws + off);     off = alignup(off + (size_t)N * 4);
  int* partial = (int*)(ws + off);    off = alignup(off + 128 * 4);
  int* csr = (int*)(ws + off);        off = alignup(off + (size_t)E * 4);
  float* aggbuf = (float*)(ws + off); off = alignup(off + (size_t)N * IN_C * 4);
  float* zbuf = (float*)(ws + off);   off = alignup(off + (size_t)N * 64 * 4);
  float* rbuf = (float*)(ws + off);   off = alignup(off + (size_t)N * 64 * 4);
  float* hbuf = (float*)(ws + off);

  int NB = (N + 1023) / 1024;  // scan chunks (<=128 supported)

  // CSR build
  hipMemsetAsync(cnt, 0, (size_t)N * 4, stream);
  k_hist<<<2048, 256, 0, stream>>>(dst, cnt, E);
  k_blocksum<<<NB, 256, 0, stream>>>(cnt, partial, N);
  k_scanpart<<<1, 128, 0, stream>>>(partial, NB);
  k_scanwrite<<<NB, 256, 0, stream>>>(cnt, partial, row_start, cursor, N);
  k_fill<<<2048, 256, 0, stream>>>(src, dst, cursor, csr, E);

  // layer 1
  k_gather1<<<(N + 3) / 4, 256, 0, stream>>>(x, csr, row_start, cnt, aggbuf, N);
  k_lin1<<<256, 512, 0, stream>>>(aggbuf, x, W1l, W1r, b1, hbuf, N);
  // layer 2
  k_lin2<<<256, 512, 0, stream>>>(hbuf, W2l, W2r, zbuf, rbuf, N);
  k_gather2b<<<(N + 3) / 4, 256, 0, stream>>>(zbuf, rbuf, b2, csr, row_start, cnt,
                                              out, N);
}